// Round 2
// baseline (1159.916 us; speedup 1.0000x reference)
//
#include <hip/hip_runtime.h>

#define HH_EPS 1e-8f

constexpr int D     = 2048;            // feature dim
constexpr int K     = 16;              // number of reflections
constexpr int R     = 2;               // rows per wave
constexpr int CH    = D / (64 * 4);    // 8 float4 chunks per lane per row
constexpr int NROWS = 4 * 4096;        // B * S = 16384
constexpr int GV    = 4;               // vectors staged per LDS group
constexpr int NG    = K / GV;          // 4 stage groups
constexpr int WPB   = 4;               // waves per block (256 threads)

// ---------------------------------------------------------------------------
// Kernel 1: Gram matrix G[i][j] = v_i . v_j  (one wave per (i,j) pair).
// Diagonal doubles as the squared norms.
// ---------------------------------------------------------------------------
__global__ void __launch_bounds__(64) hh_gram_kernel(const float* __restrict__ vecs,
                                                     float* __restrict__ G) {
    int i = blockIdx.x >> 4, j = blockIdx.x & 15;
    int lane = threadIdx.x;
    const float4* a = (const float4*)(vecs + i * D);
    const float4* b = (const float4*)(vecs + j * D);
    float s = 0.f;
#pragma unroll
    for (int c = 0; c < CH; ++c) {
        float4 x = a[c * 64 + lane], y = b[c * 64 + lane];
        s += x.x * y.x + x.y * y.y + x.z * y.z + x.w * y.w;
    }
#pragma unroll
    for (int off = 32; off >= 1; off >>= 1) s += __shfl_xor(s, off);
    if (lane == 0) G[i * K + j] = s;
}

// ---------------------------------------------------------------------------
// Kernel 2: build T (upper triangular) with H0 H1 ... H15 = I - V T V^T
// (LAPACK larft, forward columnwise):
//   T[k][k] = beta_k = 2 / max(G[k][k], EPS)
//   T[i][k] = -beta_k * sum_{j=i}^{k-1} T[i][j] * G[j][k]   (i < k)
// FIX (R1): launch with 256 threads — K*K = 256 elements of sG/sT must be
// loaded/zeroed/stored; the 64-thread version left 192 elements garbage.
// ---------------------------------------------------------------------------
__global__ void __launch_bounds__(256) hh_buildT_kernel(const float* __restrict__ G,
                                                        float* __restrict__ T) {
    __shared__ float sG[K * K], sT[K * K];
    int t = threadIdx.x;
    if (t < K * K) { sG[t] = G[t]; sT[t] = 0.f; }
    __syncthreads();
    for (int k = 0; k < K; ++k) {
        float beta = 2.f / fmaxf(sG[k * K + k], HH_EPS);
        if (t == k) sT[k * K + k] = beta;
        else if (t < k) {
            float s = 0.f;
            for (int j = t; j < k; ++j) s += sT[t * K + j] * sG[j * K + k];
            sT[t * K + k] = -beta * s;
        }
        __syncthreads();
    }
    if (t < K * K) T[t] = sT[t];
}

// ---------------------------------------------------------------------------
// LDS staging: one group of GV=4 vectors (32 KB) via global_load_lds width-16.
// Linear LDS dest (wave-uniform base + lane*16, lanes contiguous) +
// contiguous global source (rule #21: both sides linear).
// ---------------------------------------------------------------------------
__device__ __forceinline__ void stage_group(const float4* __restrict__ vsrc,
                                            float4* svp, int g, int t) {
    const float4* src = vsrc + g * (GV * D / 4);
#pragma unroll
    for (int i = 0; i < (GV * D / 4) / 256; ++i) {   // 8 iterations
        int idx = t + i * 256;
        __builtin_amdgcn_global_load_lds(
            (const __attribute__((address_space(1))) unsigned int*)(src + idx),
            (__attribute__((address_space(3))) unsigned int*)(svp + idx),
            16, 0, 0);
    }
}

// ---------------------------------------------------------------------------
// Main kernel: compact-WY application. Each wave owns R=2 rows in registers.
//   p[r][k] = row_r . v_k        (16 independent dots, one butterfly reduce)
//   w = p . T                    (in-place, triangular)
//   row_r -= sum_k w[r][k] v_k   (rank-16 update, one ILP-rich pass)
// V streamed through 32 KB LDS in 4-vector groups: dot uses groups 0..3,
// update reuses group 3 (still resident) then restages 2,1,0.
// ---------------------------------------------------------------------------
__global__ void __launch_bounds__(256, 3)
hh_apply_wy(const float* __restrict__ h_in, const float* __restrict__ vecs,
            const float* __restrict__ Tmat, float* __restrict__ h_out) {
    __shared__ float4 sv[GV * (D / 4)];   // 32 KB: 4 staged vectors
    __shared__ float  sT[K * K];          // 1 KB: T matrix

    const int t    = threadIdx.x;
    const int wave = t >> 6;
    const int lane = t & 63;
    const int gw   = blockIdx.x * WPB + wave;     // global wave id
    const size_t rbase = (size_t)gw * R;          // first row of this wave

    // Issue h-row loads first (HBM latency hides under staging + barrier).
    float4 h[R][CH];
    const float4* hin4 = (const float4*)h_in;
#pragma unroll
    for (int r = 0; r < R; ++r)
#pragma unroll
        for (int j = 0; j < CH; ++j)
            h[r][j] = hin4[(rbase + r) * (D / 4) + j * 64 + lane];

    if (t < K * K) sT[t] = Tmat[t];

    const float4* v4 = (const float4*)vecs;
    stage_group(v4, sv, 0, t);
    __syncthreads();   // drains vmcnt(0): h loads + staged group 0 + sT

    // ---- dot pass: p[r][k] (per-lane partials) -------------------------
    float P[R][K];
#pragma unroll
    for (int g = 0; g < NG; ++g) {
#pragma unroll
        for (int lv = 0; lv < GV; ++lv) {
            const int k = g * GV + lv;
            float4 a0 = {0.f, 0.f, 0.f, 0.f}, a1 = {0.f, 0.f, 0.f, 0.f};
#pragma unroll
            for (int j = 0; j < CH; ++j) {
                float4 v = sv[lv * (D / 4) + j * 64 + lane];
                a0.x += h[0][j].x * v.x; a0.y += h[0][j].y * v.y;
                a0.z += h[0][j].z * v.z; a0.w += h[0][j].w * v.w;
                a1.x += h[1][j].x * v.x; a1.y += h[1][j].y * v.y;
                a1.z += h[1][j].z * v.z; a1.w += h[1][j].w * v.w;
            }
            P[0][k] = (a0.x + a0.y) + (a0.z + a0.w);
            P[1][k] = (a1.x + a1.y) + (a1.z + a1.w);
        }
        if (g < NG - 1) {
            __syncthreads();
            stage_group(v4, sv, g + 1, t);
            __syncthreads();
        }
    }

    // ---- ONE wave-wide butterfly reduce of all 32 partials -------------
#pragma unroll
    for (int off = 32; off >= 1; off >>= 1)
#pragma unroll
        for (int r = 0; r < R; ++r)
#pragma unroll
            for (int k = 0; k < K; ++k)
                P[r][k] += __shfl_xor(P[r][k], off);

    // ---- w = p . T, in place (T upper triangular: k <= j contribute).
    // Descending j: P[r][j] overwritten only after all its uses.
#pragma unroll
    for (int j = K - 1; j >= 0; --j) {
        float s0 = 0.f, s1 = 0.f;
#pragma unroll
        for (int k = 0; k <= j; ++k) {
            float tk = sT[k * K + j];   // uniform address -> LDS broadcast
            s0 += P[0][k] * tk;
            s1 += P[1][k] * tk;
        }
        P[0][j] = s0; P[1][j] = s1;
    }

    // ---- rank-16 update: group 3 still in LDS, then restage 2,1,0 ------
#pragma unroll
    for (int gg = 0; gg < NG; ++gg) {
        const int g = NG - 1 - gg;
#pragma unroll
        for (int lv = 0; lv < GV; ++lv) {
            const int k = g * GV + lv;
            const float w0 = P[0][k], w1 = P[1][k];
#pragma unroll
            for (int j = 0; j < CH; ++j) {
                float4 v = sv[lv * (D / 4) + j * 64 + lane];
                h[0][j].x -= w0 * v.x; h[0][j].y -= w0 * v.y;
                h[0][j].z -= w0 * v.z; h[0][j].w -= w0 * v.w;
                h[1][j].x -= w1 * v.x; h[1][j].y -= w1 * v.y;
                h[1][j].z -= w1 * v.z; h[1][j].w -= w1 * v.w;
            }
        }
        if (g > 0) {
            __syncthreads();
            stage_group(v4, sv, g - 1, t);
            __syncthreads();
        }
    }

    // ---- write back ----------------------------------------------------
    float4* out4 = (float4*)h_out;
#pragma unroll
    for (int r = 0; r < R; ++r)
#pragma unroll
        for (int j = 0; j < CH; ++j)
            out4[(rbase + r) * (D / 4) + j * 64 + lane] = h[r][j];
}

extern "C" void kernel_launch(void* const* d_in, const int* in_sizes, int n_in,
                              void* d_out, int out_size, void* d_ws, size_t ws_size,
                              hipStream_t stream) {
    const float* h    = (const float*)d_in[0];   // [4,4096,2048] fp32
    const float* vecs = (const float*)d_in[1];   // [16,2048] fp32
    float* out        = (float*)d_out;           // [4,4096,2048] fp32

    float* G  = (float*)d_ws;                    // 256 floats
    float* Tm = G + K * K;                       // 256 floats

    hh_gram_kernel<<<K * K, 64, 0, stream>>>(vecs, G);
    hh_buildT_kernel<<<1, 256, 0, stream>>>(G, Tm);

    int blocks = NROWS / (R * WPB);              // 2048 blocks of 4 waves
    hh_apply_wy<<<blocks, 256, 0, stream>>>(h, vecs, Tm, out);
}

// Round 3
// 536.115 us; speedup vs baseline: 2.1636x; 2.1636x over previous
//
#include <hip/hip_runtime.h>

#define HH_EPS 1e-8f

constexpr int D     = 2048;            // feature dim
constexpr int K     = 16;              // number of reflections
constexpr int R     = 2;               // rows per wave
constexpr int CH    = D / (64 * 4);    // 8 float4 chunks per lane per row
constexpr int NROWS = 4 * 4096;        // B * S = 16384
constexpr int GV    = 4;               // vectors staged per LDS group
constexpr int NG    = K / GV;          // 4 stage groups
constexpr int WPB   = 4;               // waves per block (256 threads)

// ---------------------------------------------------------------------------
// Kernel 1: Gram matrix G[i][j] = v_i . v_j  (one wave per (i,j) pair).
// ---------------------------------------------------------------------------
__global__ void __launch_bounds__(64) hh_gram_kernel(const float* __restrict__ vecs,
                                                     float* __restrict__ G) {
    int i = blockIdx.x >> 4, j = blockIdx.x & 15;
    int lane = threadIdx.x;
    const float4* a = (const float4*)(vecs + i * D);
    const float4* b = (const float4*)(vecs + j * D);
    float s = 0.f;
#pragma unroll
    for (int c = 0; c < CH; ++c) {
        float4 x = a[c * 64 + lane], y = b[c * 64 + lane];
        s += x.x * y.x + x.y * y.y + x.z * y.z + x.w * y.w;
    }
#pragma unroll
    for (int off = 32; off >= 1; off >>= 1) s += __shfl_xor(s, off);
    if (lane == 0) G[i * K + j] = s;
}

// ---------------------------------------------------------------------------
// Kernel 2: build T (upper triangular): H0..H15 = I - V T V^T (larft).
//   T[k][k] = beta_k = 2 / max(G[k][k], EPS)
//   T[i][k] = -beta_k * sum_{j=i}^{k-1} T[i][j] * G[j][k]   (i < k)
// 256 threads: t covers all K*K elements for load/zero/store.
// ---------------------------------------------------------------------------
__global__ void __launch_bounds__(256) hh_buildT_kernel(const float* __restrict__ G,
                                                        float* __restrict__ T) {
    __shared__ float sG[K * K], sT[K * K];
    int t = threadIdx.x;
    sG[t] = G[t]; sT[t] = 0.f;
    __syncthreads();
    for (int k = 0; k < K; ++k) {
        float beta = 2.f / fmaxf(sG[k * K + k], HH_EPS);
        if (t == k) sT[k * K + k] = beta;
        else if (t < k) {
            float s = 0.f;
            for (int j = t; j < k; ++j) s += sT[t * K + j] * sG[j * K + k];
            sT[t * K + k] = -beta * s;
        }
        __syncthreads();
    }
    T[t] = sT[t];
}

// ---------------------------------------------------------------------------
// LDS staging: one group of GV=4 vectors (32 KB) via global_load_lds w=16.
// Linear LDS dest (wave-uniform base + lane*16) + contiguous global source.
// ---------------------------------------------------------------------------
__device__ __forceinline__ void stage_group(const float4* __restrict__ vsrc,
                                            float4* svp, int g, int t) {
    const float4* src = vsrc + g * (GV * D / 4);
#pragma unroll
    for (int i = 0; i < (GV * D / 4) / 256; ++i) {   // 8 iterations
        int idx = t + i * 256;
        __builtin_amdgcn_global_load_lds(
            (const __attribute__((address_space(1))) unsigned int*)(src + idx),
            (__attribute__((address_space(3))) unsigned int*)(svp + idx),
            16, 0, 0);
    }
}

// ---------------------------------------------------------------------------
// Main kernel: compact-WY. Each wave owns R=2 rows in registers.
//   p[r][k] = row_r . v_k     (independent dots; per-GROUP butterfly reduce
//                              overlapped with next group's staging loads)
//   w = p . T                 (in-place triangular)
//   row_r -= sum_k w[r][k] v_k
// launch_bounds(256,2): 256-VGPR budget. R2's (256,3) capped at 168 and
// spilled h to scratch -> 3.3 GB HBM traffic. Do not lower this again
// without checking peak liveness.
// ---------------------------------------------------------------------------
__global__ void __launch_bounds__(256, 2)
hh_apply_wy(const float* __restrict__ h_in, const float* __restrict__ vecs,
            const float* __restrict__ Tmat, float* __restrict__ h_out) {
    __shared__ float4 sv[GV * (D / 4)];   // 32 KB: 4 staged vectors
    __shared__ float  sT[K * K];          // 1 KB: T matrix

    const int t    = threadIdx.x;
    const int wave = t >> 6;
    const int lane = t & 63;
    const int gw   = blockIdx.x * WPB + wave;     // global wave id
    const size_t rbase = (size_t)gw * R;          // first row of this wave

    // Issue h-row loads first (HBM latency hides under staging + barrier).
    float4 h[R][CH];
    const float4* hin4 = (const float4*)h_in;
#pragma unroll
    for (int r = 0; r < R; ++r)
#pragma unroll
        for (int j = 0; j < CH; ++j)
            h[r][j] = hin4[(rbase + r) * (D / 4) + j * 64 + lane];

    sT[t] = Tmat[t];

    const float4* v4 = (const float4*)vecs;
    stage_group(v4, sv, 0, t);
    __syncthreads();   // drains vmcnt(0): h loads + staged group 0 + sT

    // ---- dot pass ------------------------------------------------------
    float P[R][K];
#pragma unroll
    for (int g = 0; g < NG; ++g) {
#pragma unroll
        for (int lv = 0; lv < GV; ++lv) {
            const int k = g * GV + lv;
            float4 a0 = {0.f, 0.f, 0.f, 0.f}, a1 = {0.f, 0.f, 0.f, 0.f};
#pragma unroll
            for (int j = 0; j < CH; ++j) {
                float4 v = sv[lv * (D / 4) + j * 64 + lane];
                a0.x += h[0][j].x * v.x; a0.y += h[0][j].y * v.y;
                a0.z += h[0][j].z * v.z; a0.w += h[0][j].w * v.w;
                a1.x += h[1][j].x * v.x; a1.y += h[1][j].y * v.y;
                a1.z += h[1][j].z * v.z; a1.w += h[1][j].w * v.w;
            }
            P[0][k] = (a0.x + a0.y) + (a0.z + a0.w);
            P[1][k] = (a1.x + a1.y) + (a1.z + a1.w);
        }
        // Overlap: barrier, issue next stage, THEN reduce this group's 8
        // partials (VALU shuffles run while the loads are in flight).
        if (g < NG - 1) {
            __syncthreads();
            stage_group(v4, sv, g + 1, t);
        }
#pragma unroll
        for (int off = 32; off >= 1; off >>= 1)
#pragma unroll
            for (int r = 0; r < R; ++r)
#pragma unroll
                for (int lv = 0; lv < GV; ++lv)
                    P[r][g * GV + lv] += __shfl_xor(P[r][g * GV + lv], off);
        if (g < NG - 1) __syncthreads();
    }

    // ---- w = p . T, in place (T upper triangular; descending j is safe).
#pragma unroll
    for (int j = K - 1; j >= 0; --j) {
        float s0 = 0.f, s1 = 0.f;
#pragma unroll
        for (int k = 0; k <= j; ++k) {
            float tk = sT[k * K + j];   // uniform address -> LDS broadcast
            s0 += P[0][k] * tk;
            s1 += P[1][k] * tk;
        }
        P[0][j] = s0; P[1][j] = s1;
    }

    // ---- rank-16 update: group 3 still in LDS, then restage 2,1,0 ------
#pragma unroll
    for (int gg = 0; gg < NG; ++gg) {
        const int g = NG - 1 - gg;
#pragma unroll
        for (int lv = 0; lv < GV; ++lv) {
            const int k = g * GV + lv;
            const float w0 = P[0][k], w1 = P[1][k];
#pragma unroll
            for (int j = 0; j < CH; ++j) {
                float4 v = sv[lv * (D / 4) + j * 64 + lane];
                h[0][j].x -= w0 * v.x; h[0][j].y -= w0 * v.y;
                h[0][j].z -= w0 * v.z; h[0][j].w -= w0 * v.w;
                h[1][j].x -= w1 * v.x; h[1][j].y -= w1 * v.y;
                h[1][j].z -= w1 * v.z; h[1][j].w -= w1 * v.w;
            }
        }
        if (g > 0) {
            __syncthreads();
            stage_group(v4, sv, g - 1, t);
            __syncthreads();
        }
    }

    // ---- write back ----------------------------------------------------
    float4* out4 = (float4*)h_out;
#pragma unroll
    for (int r = 0; r < R; ++r)
#pragma unroll
        for (int j = 0; j < CH; ++j)
            out4[(rbase + r) * (D / 4) + j * 64 + lane] = h[r][j];
}

extern "C" void kernel_launch(void* const* d_in, const int* in_sizes, int n_in,
                              void* d_out, int out_size, void* d_ws, size_t ws_size,
                              hipStream_t stream) {
    const float* h    = (const float*)d_in[0];   // [4,4096,2048] fp32
    const float* vecs = (const float*)d_in[1];   // [16,2048] fp32
    float* out        = (float*)d_out;           // [4,4096,2048] fp32

    float* G  = (float*)d_ws;                    // 256 floats
    float* Tm = G + K * K;                       // 256 floats

    hh_gram_kernel<<<K * K, 64, 0, stream>>>(vecs, G);
    hh_buildT_kernel<<<1, 256, 0, stream>>>(G, Tm);

    int blocks = NROWS / (R * WPB);              // 2048 blocks of 4 waves
    hh_apply_wy<<<blocks, 256, 0, stream>>>(h, vecs, Tm, out);
}